// Round 9
// baseline (1368.338 us; speedup 1.0000x reference)
//
#include <hip/hip_runtime.h>
#include <hip/hip_bf16.h>
#include <math.h>

#define B_  8
#define S_  512
#define H_  768
#define NH_ 12
#define D_  64
#define I_  3072
#define NTOK (B_*S_)   // 4096
#define LDQ 2304       // fused qkv row stride

typedef __attribute__((ext_vector_type(8))) __bf16 bf16x8;
typedef __attribute__((ext_vector_type(8))) unsigned short ushort8;
typedef __attribute__((ext_vector_type(4))) float  f32x4;

__device__ __forceinline__ float gelu_exact(float x) {
    return 0.5f * x * (1.0f + erff(x * 0.70710678118654752440f));
}

__device__ __forceinline__ unsigned short f2bf(float x) {
    __hip_bfloat16 h = __float2bfloat16(x);
    return *reinterpret_cast<unsigned short*>(&h);
}

__device__ __forceinline__ void gload16(const void* g, void* l) {
    __builtin_amdgcn_global_load_lds(
        (const __attribute__((address_space(1))) void*)g,
        (__attribute__((address_space(3))) void*)l,
        16, 0, 0);
}

#define SB0() __builtin_amdgcn_sched_barrier(0)

// -------------------- f32 [K][N] -> bf16 [N][K] transpose-convert --------------------
__global__ void cvtT_kernel(const float* __restrict__ W, __hip_bfloat16* __restrict__ WT,
                            int K, int N) {
    __shared__ float tile[32][33];
    int k0 = blockIdx.y * 32, n0 = blockIdx.x * 32;
    int tx = threadIdx.x & 31, ty = threadIdx.x >> 5;   // 32x8
    #pragma unroll
    for (int i = 0; i < 32; i += 8)
        tile[ty + i][tx] = W[(long)(k0 + ty + i) * N + n0 + tx];
    __syncthreads();
    #pragma unroll
    for (int i = 0; i < 32; i += 8)
        WT[(long)(n0 + ty + i) * K + k0 + tx] = __float2bfloat16(tile[tx][ty + i]);
}

// -------------------- embeddings + LayerNorm (f32 + bf16 outputs) --------------------
__global__ void embed_ln_kernel(const int* __restrict__ ids,
                                const float* __restrict__ Wword,
                                const float* __restrict__ Wpos,
                                const float* __restrict__ Wtype,
                                const float* __restrict__ g,
                                const float* __restrict__ b,
                                float* __restrict__ out,
                                __hip_bfloat16* __restrict__ outb) {
    int t = blockIdx.x;
    int s = t % S_;
    long id = ids[t];
    int tid = threadIdx.x;
    float vals[3];
    float sum = 0.f, sq = 0.f;
    #pragma unroll
    for (int i = 0; i < 3; ++i) {
        int c = tid + 256 * i;
        float e = Wword[id * H_ + c] + Wpos[(long)s * H_ + c] + Wtype[c];
        vals[i] = e; sum += e; sq += e * e;
    }
    __shared__ float r1[256], r2[256];
    r1[tid] = sum; r2[tid] = sq; __syncthreads();
    for (int st = 128; st > 0; st >>= 1) {
        if (tid < st) { r1[tid] += r1[tid + st]; r2[tid] += r2[tid + st]; }
        __syncthreads();
    }
    float mean = r1[0] * (1.0f / H_);
    float var  = r2[0] * (1.0f / H_) - mean * mean;
    float inv  = rsqrtf(var + 1e-12f);
    #pragma unroll
    for (int i = 0; i < 3; ++i) {
        int c = tid + 256 * i;
        float v = (vals[i] - mean) * inv * g[c] + b[c];
        out[(long)t * H_ + c] = v;
        outb[(long)t * H_ + c] = __float2bfloat16(v);
    }
}

// -------------------- LN(a + r) (f32 + bf16 outputs) --------------------
__global__ void add_ln_kernel(const float* __restrict__ a,
                              const float* __restrict__ r,
                              const float* __restrict__ g,
                              const float* __restrict__ bb,
                              float* __restrict__ out,
                              __hip_bfloat16* __restrict__ outb) {
    int t = blockIdx.x;
    int tid = threadIdx.x;
    float vals[3];
    float sum = 0.f, sq = 0.f;
    #pragma unroll
    for (int i = 0; i < 3; ++i) {
        int c = tid + 256 * i;
        float e = a[(long)t * H_ + c] + r[(long)t * H_ + c];
        vals[i] = e; sum += e; sq += e * e;
    }
    __shared__ float r1[256], r2[256];
    r1[tid] = sum; r2[tid] = sq; __syncthreads();
    for (int st = 128; st > 0; st >>= 1) {
        if (tid < st) { r1[tid] += r1[tid + st]; r2[tid] += r2[tid + st]; }
        __syncthreads();
    }
    float mean = r1[0] * (1.0f / H_);
    float var  = r2[0] * (1.0f / H_) - mean * mean;
    float inv  = rsqrtf(var + 1e-12f);
    #pragma unroll
    for (int i = 0; i < 3; ++i) {
        int c = tid + 256 * i;
        float v = (vals[i] - mean) * inv * g[c] + bb[c];
        out[(long)t * H_ + c] = v;
        outb[(long)t * H_ + c] = __float2bfloat16(v);
    }
}

// -------------------- LN(a + r1 + r2) (f32 + bf16 outputs) — for split-K --------------------
__global__ void add_ln3_kernel(const float* __restrict__ a,
                               const float* __restrict__ r1p,
                               const float* __restrict__ r2p,
                               const float* __restrict__ g,
                               const float* __restrict__ bb,
                               float* __restrict__ out,
                               __hip_bfloat16* __restrict__ outb) {
    int t = blockIdx.x;
    int tid = threadIdx.x;
    float vals[3];
    float sum = 0.f, sq = 0.f;
    #pragma unroll
    for (int i = 0; i < 3; ++i) {
        int c = tid + 256 * i;
        float e = a[(long)t * H_ + c] + r1p[(long)t * H_ + c] + r2p[(long)t * H_ + c];
        vals[i] = e; sum += e; sq += e * e;
    }
    __shared__ float r1[256], r2[256];
    r1[tid] = sum; r2[tid] = sq; __syncthreads();
    for (int st = 128; st > 0; st >>= 1) {
        if (tid < st) { r1[tid] += r1[tid + st]; r2[tid] += r2[tid + st]; }
        __syncthreads();
    }
    float mean = r1[0] * (1.0f / H_);
    float var  = r2[0] * (1.0f / H_) - mean * mean;
    float inv  = rsqrtf(var + 1e-12f);
    #pragma unroll
    for (int i = 0; i < 3; ++i) {
        int c = tid + 256 * i;
        float v = (vals[i] - mean) * inv * g[c] + bb[c];
        out[(long)t * H_ + c] = v;
        outb[(long)t * H_ + c] = __float2bfloat16(v);
    }
}

// ============ single-wave bf16 MFMA GEMM: 64x64 tile per 1-wave block ============
// NO barriers. Each wave owns a private 16 KB double buffer and stages its own
// A/B panels via global_load_lds. Sync is within-wave only:
//   vmcnt(8)  — current buffer's 8 DMA loads landed (next tile's 8 stay in flight)
//   lgkmcnt(0)+sched_barrier — fragment ds_reads consumed before restaging the buffer
// K-granule swizzle (HW-verified 0-conflict): LDS granule gq of row r holds global
// granule gq ^ ((r>>1)&3); read granule l4 ^ ((l15>>1)&3).
// Split-K via gridDim.z: block z does K-chunk [z*Kc,(z+1)*Kc), writes Cf + z*M*N
// (bias added only by z==0).
template<int ACT, int WF32, int WB16>
__global__ __launch_bounds__(64, 2) void wave_gemm_kernel(
    const __hip_bfloat16* __restrict__ A,
    const __hip_bfloat16* __restrict__ BT,
    const float* __restrict__ bias,
    float* __restrict__ Cf,
    __hip_bfloat16* __restrict__ Cb,
    int M, int N, int Kc, int lda, int ldb) {
    __shared__ __align__(16) unsigned short sA[2][64 * 32];
    __shared__ __align__(16) unsigned short sB[2][64 * 32];
    const int lane = threadIdx.x;
    const int l15  = lane & 15, l4 = lane >> 4;
    const int m0 = blockIdx.y * 64, n0 = blockIdx.x * 64;
    const int koff = blockIdx.z * Kc;
    const int goff = (l15 >> 1) & 3;

    auto stage = [&](int buf, int k0) {
        #pragma unroll
        for (int u = 0; u < 4; ++u) {
            int c = u * 64 + lane;
            int row = c >> 2, gq = c & 3;
            int gsrc = gq ^ ((row >> 1) & 3);
            gload16(A + (long)(m0 + row) * lda + koff + k0 + gsrc * 8, &sA[buf][c * 8]);
        }
        #pragma unroll
        for (int u = 0; u < 4; ++u) {
            int c = u * 64 + lane;
            int row = c >> 2, gq = c & 3;
            int gsrc = gq ^ ((row >> 1) & 3);
            gload16(BT + (long)(n0 + row) * ldb + koff + k0 + gsrc * 8, &sB[buf][c * 8]);
        }
    };

    f32x4 acc[4][4] = {};
    const int nk = Kc >> 5;

    stage(0, 0);
    if (nk > 1) stage(1, 32);
    for (int t = 0; t < nk; ++t) {
        const int cur = t & 1;
        if (t + 1 < nk) asm volatile("s_waitcnt vmcnt(8)" ::: "memory");
        else            asm volatile("s_waitcnt vmcnt(0)" ::: "memory");
        SB0();

        const int gsw = (l4 ^ goff) * 8;
        bf16x8 af[4], bf[4];
        #pragma unroll
        for (int i = 0; i < 4; ++i)
            af[i] = *reinterpret_cast<const bf16x8*>(&sA[cur][(i * 16 + l15) * 32 + gsw]);
        #pragma unroll
        for (int j = 0; j < 4; ++j)
            bf[j] = *reinterpret_cast<const bf16x8*>(&sB[cur][(j * 16 + l15) * 32 + gsw]);

        asm volatile("s_waitcnt lgkmcnt(0)" ::: "memory");   // frags in regs before restage
        SB0();
        if (t + 2 < nk) stage(cur, (t + 2) * 32);
        SB0();

        #pragma unroll
        for (int i = 0; i < 4; ++i)
            #pragma unroll
            for (int j = 0; j < 4; ++j)
                acc[i][j] = __builtin_amdgcn_mfma_f32_16x16x32_bf16(af[i], bf[j], acc[i][j], 0, 0, 0);
    }

    float* Cfz = Cf + (size_t)blockIdx.z * M * N;
    const bool addb = (blockIdx.z == 0);
    #pragma unroll
    for (int i = 0; i < 4; ++i) {
        #pragma unroll
        for (int j = 0; j < 4; ++j) {
            int col = n0 + j * 16 + l15;
            float bv = addb ? bias[col] : 0.f;
            #pragma unroll
            for (int r = 0; r < 4; ++r) {
                int row = m0 + i * 16 + l4 * 4 + r;
                float v = acc[i][j][r] + bv;
                if (ACT == 1) v = gelu_exact(v);
                if (WF32) Cfz[(long)row * N + col] = v;
                if (WB16) Cb[(long)row * N + col] = __float2bfloat16(v);
            }
        }
    }
}

// -------------------- fused flash attention on fused QKV buffer --------------------
__global__ __launch_bounds__(256, 4) void flash_attn_kernel(
    const __hip_bfloat16* __restrict__ QKV,
    __hip_bfloat16* __restrict__ Ctx) {
    __shared__ __align__(16) unsigned short sK[64 * 72];
    __shared__ __align__(16) unsigned short sVt[64 * 72];
    __shared__ __align__(16) unsigned short sP[4 * 16 * 72];

    const int tid  = threadIdx.x;
    const int lane = tid & 63;
    const int w    = tid >> 6;
    const int l15  = lane & 15, l4 = lane >> 4;
    const int qb = blockIdx.x;
    const int bh = blockIdx.y;
    const int b  = bh / NH_, hd = bh % NH_;
    const long rbase = (long)b * S_ * LDQ;
    const int qoff = hd * D_, koff = H_ + hd * D_, voff = 2 * H_ + hd * D_;

    const int qrow0 = qb * 64 + w * 16;
    bf16x8 af[2];
    #pragma unroll
    for (int ks = 0; ks < 2; ++ks)
        af[ks] = *reinterpret_cast<const bf16x8*>(
            QKV + rbase + (long)(qrow0 + l15) * LDQ + qoff + ks * 32 + l4 * 8);

    f32x4 ctx[4] = {};
    float m_run[4], l_run[4];
    #pragma unroll
    for (int r = 0; r < 4; ++r) { m_run[r] = -1e30f; l_run[r] = 0.f; }

    const int sr = tid >> 2;
    const int sc = (tid & 3) * 16;
    unsigned short* pl = sP + w * (16 * 72);

    for (int kv0 = 0; kv0 < S_; kv0 += 64) {
        const __hip_bfloat16* kg = QKV + rbase + (long)(kv0 + sr) * LDQ + koff + sc;
        const __hip_bfloat16* vg = QKV + rbase + (long)(kv0 + sr) * LDQ + voff + sc;
        ushort8 kv_a = *reinterpret_cast<const ushort8*>(kg);
        ushort8 kv_b = *reinterpret_cast<const ushort8*>(kg + 8);
        ushort8 vv_a = *reinterpret_cast<const ushort8*>(vg);
        ushort8 vv_b = *reinterpret_cast<const ushort8*>(vg + 8);
        __syncthreads();
        *reinterpret_cast<ushort8*>(sK + sr * 72 + sc)     = kv_a;
        *reinterpret_cast<ushort8*>(sK + sr * 72 + sc + 8) = kv_b;
        #pragma unroll
        for (int i = 0; i < 8; ++i) {
            sVt[(sc + i) * 72 + sr]     = vv_a[i];
            sVt[(sc + 8 + i) * 72 + sr] = vv_b[i];
        }
        __syncthreads();

        f32x4 s[4];
        #pragma unroll
        for (int j = 0; j < 4; ++j) {
            s[j] = (f32x4){0.f, 0.f, 0.f, 0.f};
            #pragma unroll
            for (int ks = 0; ks < 2; ++ks) {
                bf16x8 bk = *reinterpret_cast<const bf16x8*>(sK + (j * 16 + l15) * 72 + ks * 32 + l4 * 8);
                s[j] = __builtin_amdgcn_mfma_f32_16x16x32_bf16(af[ks], bk, s[j], 0, 0, 0);
            }
        }
        #pragma unroll
        for (int j = 0; j < 4; ++j) s[j] *= 0.125f;

        #pragma unroll
        for (int r = 0; r < 4; ++r) {
            float mx = fmaxf(fmaxf(s[0][r], s[1][r]), fmaxf(s[2][r], s[3][r]));
            #pragma unroll
            for (int o = 1; o < 16; o <<= 1) mx = fmaxf(mx, __shfl_xor(mx, o));
            float mnew = fmaxf(m_run[r], mx);
            float sum = 0.f;
            #pragma unroll
            for (int j = 0; j < 4; ++j) {
                float p = __expf(s[j][r] - mnew);
                s[j][r] = p; sum += p;
            }
            #pragma unroll
            for (int o = 1; o < 16; o <<= 1) sum += __shfl_xor(sum, o);
            float resc = __expf(m_run[r] - mnew);
            l_run[r] = l_run[r] * resc + sum;
            m_run[r] = mnew;
            #pragma unroll
            for (int j = 0; j < 4; ++j) ctx[j][r] *= resc;
        }

        #pragma unroll
        for (int j = 0; j < 4; ++j)
            #pragma unroll
            for (int r = 0; r < 4; ++r)
                pl[(l4 * 4 + r) * 72 + j * 16 + l15] = f2bf(s[j][r]);

        #pragma unroll
        for (int ks = 0; ks < 2; ++ks) {
            bf16x8 ap = *reinterpret_cast<const bf16x8*>(pl + l15 * 72 + ks * 32 + l4 * 8);
            #pragma unroll
            for (int jd = 0; jd < 4; ++jd) {
                bf16x8 bv = *reinterpret_cast<const bf16x8*>(sVt + (jd * 16 + l15) * 72 + ks * 32 + l4 * 8);
                ctx[jd] = __builtin_amdgcn_mfma_f32_16x16x32_bf16(ap, bv, ctx[jd], 0, 0, 0);
            }
        }
    }

    #pragma unroll
    for (int r = 0; r < 4; ++r) {
        float inv = 1.f / l_run[r];
        long tok = (long)b * S_ + qb * 64 + w * 16 + l4 * 4 + r;
        #pragma unroll
        for (int jd = 0; jd < 4; ++jd)
            Ctx[tok * H_ + hd * D_ + jd * 16 + l15] = __float2bfloat16(ctx[jd][r] * inv);
    }
}

// -------------------- pooled head --------------------
__global__ void pooled_kernel(const float* __restrict__ h,
                              const float* __restrict__ Wp,
                              const float* __restrict__ bp,
                              float* __restrict__ out) {
    int b = blockIdx.y;
    int col = blockIdx.x * 256 + threadIdx.x;
    const float* hb = h + (long)b * S_ * H_;
    float acc = 0.f;
    #pragma unroll 8
    for (int k = 0; k < H_; ++k)
        acc += hb[k] * Wp[(long)k * H_ + col];
    out[(long)b * H_ + col] = acc + bp[col];
}

extern "C" void kernel_launch(void* const* d_in, const int* in_sizes, int n_in,
                              void* d_out, int out_size, void* d_ws, size_t ws_size,
                              hipStream_t stream) {
    const int*   x      = (const int*)  d_in[0];
    const float* W_word = (const float*)d_in[1];
    const float* W_pos  = (const float*)d_in[2];
    const float* W_type = (const float*)d_in[3];
    const float* g_emb  = (const float*)d_in[4];
    const float* b_emb  = (const float*)d_in[5];
    const float* Wq     = (const float*)d_in[6];
    const float* bq     = (const float*)d_in[7];
    const float* Wk     = (const float*)d_in[8];
    const float* bk     = (const float*)d_in[9];
    const float* Wv     = (const float*)d_in[10];
    const float* bv     = (const float*)d_in[11];
    const float* Wo     = (const float*)d_in[12];
    const float* bo     = (const float*)d_in[13];
    const float* g_attn = (const float*)d_in[14];
    const float* b_attn = (const float*)d_in[15];
    const float* Wi     = (const float*)d_in[16];
    const float* bi     = (const float*)d_in[17];
    const float* Wd     = (const float*)d_in[18];
    const float* bd     = (const float*)d_in[19];
    const float* g_out  = (const float*)d_in[20];
    const float* b_out  = (const float*)d_in[21];
    const float* Wp     = (const float*)d_in[22];
    const float* bp     = (const float*)d_in[23];

    const size_t NT = (size_t)NTOK * H_;
    char* base = (char*)d_ws;
    size_t off = 0;
    auto alloc = [&](size_t bytes) -> char* {
        char* p = base + off;
        off += (bytes + 255) & ~(size_t)255;
        return p;
    };
    float* h    = (float*)alloc(NT * 4);
    float* xa   = (float*)alloc(NT * 4);
    float* kb   = (float*)alloc(NT * 4 * 2);   // split-K partials (2x)
    float* kb2  = kb + NT;
    __hip_bfloat16* h_b   = (__hip_bfloat16*)alloc(NT * 2);
    __hip_bfloat16* xa_b  = (__hip_bfloat16*)alloc(NT * 2);
    __hip_bfloat16* qkv_b = (__hip_bfloat16*)alloc((size_t)NTOK * LDQ * 2);
    __hip_bfloat16* ctx_b = (__hip_bfloat16*)alloc(NT * 2);
    __hip_bfloat16* ff1_b = (__hip_bfloat16*)alloc((size_t)NTOK * I_ * 2);
    __hip_bfloat16* WqkvT = (__hip_bfloat16*)alloc((size_t)LDQ * H_ * 2);
    __hip_bfloat16* WoT = (__hip_bfloat16*)alloc((size_t)H_ * H_ * 2);
    __hip_bfloat16* WiT = (__hip_bfloat16*)alloc((size_t)H_ * I_ * 2);
    __hip_bfloat16* WdT = (__hip_bfloat16*)alloc((size_t)I_ * H_ * 2);
    float* bqkv = (float*)alloc(LDQ * 4);

    cvtT_kernel<<<dim3(H_/32, H_/32), 256, 0, stream>>>(Wq, WqkvT, H_, H_);
    cvtT_kernel<<<dim3(H_/32, H_/32), 256, 0, stream>>>(Wk, WqkvT + (size_t)H_ * H_, H_, H_);
    cvtT_kernel<<<dim3(H_/32, H_/32), 256, 0, stream>>>(Wv, WqkvT + (size_t)2 * H_ * H_, H_, H_);
    cvtT_kernel<<<dim3(H_/32, H_/32), 256, 0, stream>>>(Wo, WoT, H_, H_);
    cvtT_kernel<<<dim3(I_/32, H_/32), 256, 0, stream>>>(Wi, WiT, H_, I_);
    cvtT_kernel<<<dim3(H_/32, I_/32), 256, 0, stream>>>(Wd, WdT, I_, H_);
    hipMemcpyAsync(bqkv,          bq, H_ * 4, hipMemcpyDeviceToDevice, stream);
    hipMemcpyAsync(bqkv + H_,     bk, H_ * 4, hipMemcpyDeviceToDevice, stream);
    hipMemcpyAsync(bqkv + 2 * H_, bv, H_ * 4, hipMemcpyDeviceToDevice, stream);

    embed_ln_kernel<<<NTOK, 256, 0, stream>>>(x, W_word, W_pos, W_type, g_emb, b_emb, h, h_b);

    dim3 gqkv(LDQ/64, NTOK/64);         // (36, 64)  = 2304 blocks
    dim3 gi(I_/64, NTOK/64);            // (48, 64)  = 3072 blocks
    dim3 go(H_/64, NTOK/64, 2);         // (12, 64, 2) = 1536 blocks, split-K=2
    dim3 gff2(H_/64, NTOK/64, 2);       // (12, 64, 2) = 1536 blocks, split-K=2
    for (int layer = 0; layer < 6; ++layer) {
        wave_gemm_kernel<0,0,1><<<gqkv, 64, 0, stream>>>(
            h_b, WqkvT, bqkv, nullptr, qkv_b, NTOK, LDQ, H_, H_, H_);
        flash_attn_kernel<<<dim3(S_/64, B_*NH_), 256, 0, stream>>>(qkv_b, ctx_b);
        wave_gemm_kernel<0,1,0><<<go, 64, 0, stream>>>(
            ctx_b, WoT, bo, kb, nullptr, NTOK, H_, H_/2, H_, H_);
        add_ln3_kernel<<<NTOK, 256, 0, stream>>>(h, kb, kb2, g_attn, b_attn, xa, xa_b);
        wave_gemm_kernel<1,0,1><<<gi, 64, 0, stream>>>(
            xa_b, WiT, bi, nullptr, ff1_b, NTOK, I_, H_, H_, H_);
        wave_gemm_kernel<0,1,0><<<gff2, 64, 0, stream>>>(
            ff1_b, WdT, bd, kb, nullptr, NTOK, H_, I_/2, I_, I_);
        add_ln3_kernel<<<NTOK, 256, 0, stream>>>(xa, kb, kb2, g_out, b_out, h, h_b);
    }

    hipMemcpyAsync(d_out, h, NT * sizeof(float), hipMemcpyDeviceToDevice, stream);
    pooled_kernel<<<dim3(3, 8), 256, 0, stream>>>(h, Wp, bp, (float*)d_out + NT);
}

// Round 10
// 1141.918 us; speedup vs baseline: 1.1983x; 1.1983x over previous
//
#include <hip/hip_runtime.h>
#include <hip/hip_bf16.h>
#include <math.h>

#define B_  8
#define S_  512
#define H_  768
#define NH_ 12
#define D_  64
#define I_  3072
#define NTOK (B_*S_)   // 4096
#define LDQ 2304       // fused qkv row stride

typedef __attribute__((ext_vector_type(8))) __bf16 bf16x8;
typedef __attribute__((ext_vector_type(8))) unsigned short ushort8;
typedef __attribute__((ext_vector_type(4))) float  f32x4;

__device__ __forceinline__ float gelu_exact(float x) {
    return 0.5f * x * (1.0f + erff(x * 0.70710678118654752440f));
}

__device__ __forceinline__ unsigned short f2bf(float x) {
    __hip_bfloat16 h = __float2bfloat16(x);
    return *reinterpret_cast<unsigned short*>(&h);
}

__device__ __forceinline__ void gload16(const void* g, void* l) {
    __builtin_amdgcn_global_load_lds(
        (const __attribute__((address_space(1))) void*)g,
        (__attribute__((address_space(3))) void*)l,
        16, 0, 0);
}

#define SB0() __builtin_amdgcn_sched_barrier(0)

// -------------------- f32 [K][N] -> bf16 [N][K] transpose-convert --------------------
__global__ void cvtT_kernel(const float* __restrict__ W, __hip_bfloat16* __restrict__ WT,
                            int K, int N) {
    __shared__ float tile[32][33];
    int k0 = blockIdx.y * 32, n0 = blockIdx.x * 32;
    int tx = threadIdx.x & 31, ty = threadIdx.x >> 5;   // 32x8
    #pragma unroll
    for (int i = 0; i < 32; i += 8)
        tile[ty + i][tx] = W[(long)(k0 + ty + i) * N + n0 + tx];
    __syncthreads();
    #pragma unroll
    for (int i = 0; i < 32; i += 8)
        WT[(long)(n0 + ty + i) * K + k0 + tx] = __float2bfloat16(tile[tx][ty + i]);
}

// -------------------- embeddings + LayerNorm (f32 + bf16 outputs) --------------------
__global__ void embed_ln_kernel(const int* __restrict__ ids,
                                const float* __restrict__ Wword,
                                const float* __restrict__ Wpos,
                                const float* __restrict__ Wtype,
                                const float* __restrict__ g,
                                const float* __restrict__ b,
                                float* __restrict__ out,
                                __hip_bfloat16* __restrict__ outb) {
    int t = blockIdx.x;
    int s = t % S_;
    long id = ids[t];
    int tid = threadIdx.x;
    float vals[3];
    float sum = 0.f, sq = 0.f;
    #pragma unroll
    for (int i = 0; i < 3; ++i) {
        int c = tid + 256 * i;
        float e = Wword[id * H_ + c] + Wpos[(long)s * H_ + c] + Wtype[c];
        vals[i] = e; sum += e; sq += e * e;
    }
    __shared__ float r1[256], r2[256];
    r1[tid] = sum; r2[tid] = sq; __syncthreads();
    for (int st = 128; st > 0; st >>= 1) {
        if (tid < st) { r1[tid] += r1[tid + st]; r2[tid] += r2[tid + st]; }
        __syncthreads();
    }
    float mean = r1[0] * (1.0f / H_);
    float var  = r2[0] * (1.0f / H_) - mean * mean;
    float inv  = rsqrtf(var + 1e-12f);
    #pragma unroll
    for (int i = 0; i < 3; ++i) {
        int c = tid + 256 * i;
        float v = (vals[i] - mean) * inv * g[c] + b[c];
        out[(long)t * H_ + c] = v;
        outb[(long)t * H_ + c] = __float2bfloat16(v);
    }
}

// -------------------- LN(a + r) (f32 + bf16 outputs) --------------------
__global__ void add_ln_kernel(const float* __restrict__ a,
                              const float* __restrict__ r,
                              const float* __restrict__ g,
                              const float* __restrict__ bb,
                              float* __restrict__ out,
                              __hip_bfloat16* __restrict__ outb) {
    int t = blockIdx.x;
    int tid = threadIdx.x;
    float vals[3];
    float sum = 0.f, sq = 0.f;
    #pragma unroll
    for (int i = 0; i < 3; ++i) {
        int c = tid + 256 * i;
        float e = a[(long)t * H_ + c] + r[(long)t * H_ + c];
        vals[i] = e; sum += e; sq += e * e;
    }
    __shared__ float r1[256], r2[256];
    r1[tid] = sum; r2[tid] = sq; __syncthreads();
    for (int st = 128; st > 0; st >>= 1) {
        if (tid < st) { r1[tid] += r1[tid + st]; r2[tid] += r2[tid + st]; }
        __syncthreads();
    }
    float mean = r1[0] * (1.0f / H_);
    float var  = r2[0] * (1.0f / H_) - mean * mean;
    float inv  = rsqrtf(var + 1e-12f);
    #pragma unroll
    for (int i = 0; i < 3; ++i) {
        int c = tid + 256 * i;
        float v = (vals[i] - mean) * inv * g[c] + bb[c];
        out[(long)t * H_ + c] = v;
        outb[(long)t * H_ + c] = __float2bfloat16(v);
    }
}

// -------------------- LN(a + r1 + r2) (f32 + bf16 outputs) — for split-K --------------------
__global__ void add_ln3_kernel(const float* __restrict__ a,
                               const float* __restrict__ r1p,
                               const float* __restrict__ r2p,
                               const float* __restrict__ g,
                               const float* __restrict__ bb,
                               float* __restrict__ out,
                               __hip_bfloat16* __restrict__ outb) {
    int t = blockIdx.x;
    int tid = threadIdx.x;
    float vals[3];
    float sum = 0.f, sq = 0.f;
    #pragma unroll
    for (int i = 0; i < 3; ++i) {
        int c = tid + 256 * i;
        float e = a[(long)t * H_ + c] + r1p[(long)t * H_ + c] + r2p[(long)t * H_ + c];
        vals[i] = e; sum += e; sq += e * e;
    }
    __shared__ float r1[256], r2[256];
    r1[tid] = sum; r2[tid] = sq; __syncthreads();
    for (int st = 128; st > 0; st >>= 1) {
        if (tid < st) { r1[tid] += r1[tid + st]; r2[tid] += r2[tid + st]; }
        __syncthreads();
    }
    float mean = r1[0] * (1.0f / H_);
    float var  = r2[0] * (1.0f / H_) - mean * mean;
    float inv  = rsqrtf(var + 1e-12f);
    #pragma unroll
    for (int i = 0; i < 3; ++i) {
        int c = tid + 256 * i;
        float v = (vals[i] - mean) * inv * g[c] + bb[c];
        out[(long)t * H_ + c] = v;
        outb[(long)t * H_ + c] = __float2bfloat16(v);
    }
}

// ============ bf16 MFMA GEMM: 128x64 tiles, swizzled LDS, 2-buffer counted vmcnt ============
// Small LDS (24 KB) -> 6 blocks/CU -> up to 24 waves/CU (occupancy is the lever this round).
// BM = 16*MI*WR, BN = 16*NJ*WC, WR*WC = 4 waves, BK = 32.
// K-granule swizzle (HW-verified 0-conflict): LDS granule gq of row r holds global granule
// gq ^ ((r>>1)&3); read granule l4 ^ ((l15>>1)&3).
// Split-K via gridDim.z: block z does K-chunk [z*Kc,(z+1)*Kc) -> Cf + z*M*N (bias on z==0).
template<int BM, int BN, int MI, int NJ, int ACT, int WF32, int WB16>
__global__ __launch_bounds__(256, 6) void mfma_gemm_kernel(
    const __hip_bfloat16* __restrict__ A,
    const __hip_bfloat16* __restrict__ BT,
    const float* __restrict__ bias,
    float* __restrict__ Cf,
    __hip_bfloat16* __restrict__ Cb,
    int M, int N, int Kc, int lda, int ldb) {
    constexpr int WC = BN / (NJ * 16);
    constexpr int WR = BM / (MI * 16);
    static_assert(WR * WC == 4, "4 waves");
    constexpr int LA = BM * 4 / 256;
    constexpr int LB = BN * 4 / 256;
    constexpr int L  = LA + LB;
    __shared__ __align__(16) __hip_bfloat16 sA[2][BM * 32];
    __shared__ __align__(16) __hip_bfloat16 sB[2][BN * 32];
    const int tid  = threadIdx.x;
    const int lane = tid & 63;
    const int w    = tid >> 6;
    const int wr   = w / WC, wc = w % WC;
    const int l15  = lane & 15, l4 = lane >> 4;
    const int m0 = blockIdx.y * BM, n0 = blockIdx.x * BN;
    const int koff = blockIdx.z * Kc;
    const int goff = (l15 >> 1) & 3;

    auto stage = [&](int buf, int k0) {
        #pragma unroll
        for (int t = 0; t < LA; ++t) {
            int c = tid + 256 * t;
            int row = c >> 2, gq = c & 3;
            int gsrc = gq ^ ((row >> 1) & 3);
            gload16(A + (long)(m0 + row) * lda + koff + k0 + gsrc * 8, &sA[buf][row * 32 + gq * 8]);
        }
        #pragma unroll
        for (int t = 0; t < LB; ++t) {
            int c = tid + 256 * t;
            int row = c >> 2, gq = c & 3;
            int gsrc = gq ^ ((row >> 1) & 3);
            gload16(BT + (long)(n0 + row) * ldb + koff + k0 + gsrc * 8, &sB[buf][row * 32 + gq * 8]);
        }
    };

    f32x4 acc[MI][NJ] = {};
    const int nk = Kc >> 5;

    stage(0, 0);
    for (int t = 0; t < nk; ++t) {
        const int cur = t & 1;
        if (t + 1 < nk) {
            stage(cur ^ 1, (t + 1) * 32);                // next tile stays in flight
            asm volatile("s_waitcnt vmcnt(%0)" :: "i"(L) : "memory");
        } else {
            asm volatile("s_waitcnt vmcnt(0)" ::: "memory");
        }
        SB0(); __builtin_amdgcn_s_barrier(); SB0();

        const int gsw = (l4 ^ goff) * 8;
        bf16x8 af[MI], bf[NJ];
        #pragma unroll
        for (int i = 0; i < MI; ++i)
            af[i] = *reinterpret_cast<const bf16x8*>(&sA[cur][(wr * MI * 16 + i * 16 + l15) * 32 + gsw]);
        #pragma unroll
        for (int j = 0; j < NJ; ++j)
            bf[j] = *reinterpret_cast<const bf16x8*>(&sB[cur][(wc * NJ * 16 + j * 16 + l15) * 32 + gsw]);
        #pragma unroll
        for (int i = 0; i < MI; ++i)
            #pragma unroll
            for (int j = 0; j < NJ; ++j)
                acc[i][j] = __builtin_amdgcn_mfma_f32_16x16x32_bf16(af[i], bf[j], acc[i][j], 0, 0, 0);

        SB0(); __builtin_amdgcn_s_barrier(); SB0();
    }

    float* Cfz = Cf + (size_t)blockIdx.z * M * N;
    const bool addb = (blockIdx.z == 0);
    #pragma unroll
    for (int i = 0; i < MI; ++i) {
        #pragma unroll
        for (int j = 0; j < NJ; ++j) {
            int col = n0 + wc * NJ * 16 + j * 16 + l15;
            float bv = addb ? bias[col] : 0.f;
            #pragma unroll
            for (int r = 0; r < 4; ++r) {
                int row = m0 + wr * MI * 16 + i * 16 + l4 * 4 + r;
                float v = acc[i][j][r] + bv;
                if (ACT == 1) v = gelu_exact(v);
                if (WF32) Cfz[(long)row * N + col] = v;
                if (WB16) Cb[(long)row * N + col] = __float2bfloat16(v);
            }
        }
    }
}

// -------------------- fused flash attention on fused QKV buffer --------------------
__global__ __launch_bounds__(256, 4) void flash_attn_kernel(
    const __hip_bfloat16* __restrict__ QKV,
    __hip_bfloat16* __restrict__ Ctx) {
    __shared__ __align__(16) unsigned short sK[64 * 72];
    __shared__ __align__(16) unsigned short sVt[64 * 72];
    __shared__ __align__(16) unsigned short sP[4 * 16 * 72];

    const int tid  = threadIdx.x;
    const int lane = tid & 63;
    const int w    = tid >> 6;
    const int l15  = lane & 15, l4 = lane >> 4;
    const int qb = blockIdx.x;
    const int bh = blockIdx.y;
    const int b  = bh / NH_, hd = bh % NH_;
    const long rbase = (long)b * S_ * LDQ;
    const int qoff = hd * D_, koff = H_ + hd * D_, voff = 2 * H_ + hd * D_;

    const int qrow0 = qb * 64 + w * 16;
    bf16x8 af[2];
    #pragma unroll
    for (int ks = 0; ks < 2; ++ks)
        af[ks] = *reinterpret_cast<const bf16x8*>(
            QKV + rbase + (long)(qrow0 + l15) * LDQ + qoff + ks * 32 + l4 * 8);

    f32x4 ctx[4] = {};
    float m_run[4], l_run[4];
    #pragma unroll
    for (int r = 0; r < 4; ++r) { m_run[r] = -1e30f; l_run[r] = 0.f; }

    const int sr = tid >> 2;
    const int sc = (tid & 3) * 16;
    unsigned short* pl = sP + w * (16 * 72);

    for (int kv0 = 0; kv0 < S_; kv0 += 64) {
        const __hip_bfloat16* kg = QKV + rbase + (long)(kv0 + sr) * LDQ + koff + sc;
        const __hip_bfloat16* vg = QKV + rbase + (long)(kv0 + sr) * LDQ + voff + sc;
        ushort8 kv_a = *reinterpret_cast<const ushort8*>(kg);
        ushort8 kv_b = *reinterpret_cast<const ushort8*>(kg + 8);
        ushort8 vv_a = *reinterpret_cast<const ushort8*>(vg);
        ushort8 vv_b = *reinterpret_cast<const ushort8*>(vg + 8);
        __syncthreads();
        *reinterpret_cast<ushort8*>(sK + sr * 72 + sc)     = kv_a;
        *reinterpret_cast<ushort8*>(sK + sr * 72 + sc + 8) = kv_b;
        #pragma unroll
        for (int i = 0; i < 8; ++i) {
            sVt[(sc + i) * 72 + sr]     = vv_a[i];
            sVt[(sc + 8 + i) * 72 + sr] = vv_b[i];
        }
        __syncthreads();

        f32x4 s[4];
        #pragma unroll
        for (int j = 0; j < 4; ++j) {
            s[j] = (f32x4){0.f, 0.f, 0.f, 0.f};
            #pragma unroll
            for (int ks = 0; ks < 2; ++ks) {
                bf16x8 bk = *reinterpret_cast<const bf16x8*>(sK + (j * 16 + l15) * 72 + ks * 32 + l4 * 8);
                s[j] = __builtin_amdgcn_mfma_f32_16x16x32_bf16(af[ks], bk, s[j], 0, 0, 0);
            }
        }
        #pragma unroll
        for (int j = 0; j < 4; ++j) s[j] *= 0.125f;

        #pragma unroll
        for (int r = 0; r < 4; ++r) {
            float mx = fmaxf(fmaxf(s[0][r], s[1][r]), fmaxf(s[2][r], s[3][r]));
            #pragma unroll
            for (int o = 1; o < 16; o <<= 1) mx = fmaxf(mx, __shfl_xor(mx, o));
            float mnew = fmaxf(m_run[r], mx);
            float sum = 0.f;
            #pragma unroll
            for (int j = 0; j < 4; ++j) {
                float p = __expf(s[j][r] - mnew);
                s[j][r] = p; sum += p;
            }
            #pragma unroll
            for (int o = 1; o < 16; o <<= 1) sum += __shfl_xor(sum, o);
            float resc = __expf(m_run[r] - mnew);
            l_run[r] = l_run[r] * resc + sum;
            m_run[r] = mnew;
            #pragma unroll
            for (int j = 0; j < 4; ++j) ctx[j][r] *= resc;
        }

        #pragma unroll
        for (int j = 0; j < 4; ++j)
            #pragma unroll
            for (int r = 0; r < 4; ++r)
                pl[(l4 * 4 + r) * 72 + j * 16 + l15] = f2bf(s[j][r]);

        #pragma unroll
        for (int ks = 0; ks < 2; ++ks) {
            bf16x8 ap = *reinterpret_cast<const bf16x8*>(pl + l15 * 72 + ks * 32 + l4 * 8);
            #pragma unroll
            for (int jd = 0; jd < 4; ++jd) {
                bf16x8 bv = *reinterpret_cast<const bf16x8*>(sVt + (jd * 16 + l15) * 72 + ks * 32 + l4 * 8);
                ctx[jd] = __builtin_amdgcn_mfma_f32_16x16x32_bf16(ap, bv, ctx[jd], 0, 0, 0);
            }
        }
    }

    #pragma unroll
    for (int r = 0; r < 4; ++r) {
        float inv = 1.f / l_run[r];
        long tok = (long)b * S_ + qb * 64 + w * 16 + l4 * 4 + r;
        #pragma unroll
        for (int jd = 0; jd < 4; ++jd)
            Ctx[tok * H_ + hd * D_ + jd * 16 + l15] = __float2bfloat16(ctx[jd][r] * inv);
    }
}

// -------------------- pooled head --------------------
__global__ void pooled_kernel(const float* __restrict__ h,
                              const float* __restrict__ Wp,
                              const float* __restrict__ bp,
                              float* __restrict__ out) {
    int b = blockIdx.y;
    int col = blockIdx.x * 256 + threadIdx.x;
    const float* hb = h + (long)b * S_ * H_;
    float acc = 0.f;
    #pragma unroll 8
    for (int k = 0; k < H_; ++k)
        acc += hb[k] * Wp[(long)k * H_ + col];
    out[(long)b * H_ + col] = acc + bp[col];
}

extern "C" void kernel_launch(void* const* d_in, const int* in_sizes, int n_in,
                              void* d_out, int out_size, void* d_ws, size_t ws_size,
                              hipStream_t stream) {
    const int*   x      = (const int*)  d_in[0];
    const float* W_word = (const float*)d_in[1];
    const float* W_pos  = (const float*)d_in[2];
    const float* W_type = (const float*)d_in[3];
    const float* g_emb  = (const float*)d_in[4];
    const float* b_emb  = (const float*)d_in[5];
    const float* Wq     = (const float*)d_in[6];
    const float* bq     = (const float*)d_in[7];
    const float* Wk     = (const float*)d_in[8];
    const float* bk     = (const float*)d_in[9];
    const float* Wv     = (const float*)d_in[10];
    const float* bv     = (const float*)d_in[11];
    const float* Wo     = (const float*)d_in[12];
    const float* bo     = (const float*)d_in[13];
    const float* g_attn = (const float*)d_in[14];
    const float* b_attn = (const float*)d_in[15];
    const float* Wi     = (const float*)d_in[16];
    const float* bi     = (const float*)d_in[17];
    const float* Wd     = (const float*)d_in[18];
    const float* bd     = (const float*)d_in[19];
    const float* g_out  = (const float*)d_in[20];
    const float* b_out  = (const float*)d_in[21];
    const float* Wp     = (const float*)d_in[22];
    const float* bp     = (const float*)d_in[23];

    const size_t NT = (size_t)NTOK * H_;
    char* base = (char*)d_ws;
    size_t off = 0;
    auto alloc = [&](size_t bytes) -> char* {
        char* p = base + off;
        off += (bytes + 255) & ~(size_t)255;
        return p;
    };
    float* h    = (float*)alloc(NT * 4);
    float* xa   = (float*)alloc(NT * 4);
    float* kb   = (float*)alloc(NT * 4 * 2);   // split-K partials (2x)
    float* kb2  = kb + NT;
    __hip_bfloat16* h_b   = (__hip_bfloat16*)alloc(NT * 2);
    __hip_bfloat16* xa_b  = (__hip_bfloat16*)alloc(NT * 2);
    __hip_bfloat16* qkv_b = (__hip_bfloat16*)alloc((size_t)NTOK * LDQ * 2);
    __hip_bfloat16* ctx_b = (__hip_bfloat16*)alloc(NT * 2);
    __hip_bfloat16* ff1_b = (__hip_bfloat16*)alloc((size_t)NTOK * I_ * 2);
    __hip_bfloat16* WqkvT = (__hip_bfloat16*)alloc((size_t)LDQ * H_ * 2);
    __hip_bfloat16* WoT = (__hip_bfloat16*)alloc((size_t)H_ * H_ * 2);
    __hip_bfloat16* WiT = (__hip_bfloat16*)alloc((size_t)H_ * I_ * 2);
    __hip_bfloat16* WdT = (__hip_bfloat16*)alloc((size_t)I_ * H_ * 2);
    float* bqkv = (float*)alloc(LDQ * 4);

    cvtT_kernel<<<dim3(H_/32, H_/32), 256, 0, stream>>>(Wq, WqkvT, H_, H_);
    cvtT_kernel<<<dim3(H_/32, H_/32), 256, 0, stream>>>(Wk, WqkvT + (size_t)H_ * H_, H_, H_);
    cvtT_kernel<<<dim3(H_/32, H_/32), 256, 0, stream>>>(Wv, WqkvT + (size_t)2 * H_ * H_, H_, H_);
    cvtT_kernel<<<dim3(H_/32, H_/32), 256, 0, stream>>>(Wo, WoT, H_, H_);
    cvtT_kernel<<<dim3(I_/32, H_/32), 256, 0, stream>>>(Wi, WiT, H_, I_);
    cvtT_kernel<<<dim3(H_/32, I_/32), 256, 0, stream>>>(Wd, WdT, I_, H_);
    hipMemcpyAsync(bqkv,          bq, H_ * 4, hipMemcpyDeviceToDevice, stream);
    hipMemcpyAsync(bqkv + H_,     bk, H_ * 4, hipMemcpyDeviceToDevice, stream);
    hipMemcpyAsync(bqkv + 2 * H_, bv, H_ * 4, hipMemcpyDeviceToDevice, stream);

    embed_ln_kernel<<<NTOK, 256, 0, stream>>>(x, W_word, W_pos, W_type, g_emb, b_emb, h, h_b);

    dim3 gqkv(LDQ/64, NTOK/128);         // (36, 32) = 1152 blocks, 4.5/CU
    dim3 gi(I_/64, NTOK/128);            // (48, 32) = 1536 blocks, 6/CU
    dim3 go(H_/64, NTOK/128, 2);         // (12, 32, 2) = 768 blocks, split-K=2
    dim3 gff2(H_/64, NTOK/128, 2);       // (12, 32, 2) = 768 blocks, split-K=2
    for (int layer = 0; layer < 6; ++layer) {
        mfma_gemm_kernel<128,64,4,2,0,0,1><<<gqkv, 256, 0, stream>>>(
            h_b, WqkvT, bqkv, nullptr, qkv_b, NTOK, LDQ, H_, H_, H_);
        flash_attn_kernel<<<dim3(S_/64, B_*NH_), 256, 0, stream>>>(qkv_b, ctx_b);
        mfma_gemm_kernel<128,64,4,2,0,1,0><<<go, 256, 0, stream>>>(
            ctx_b, WoT, bo, kb, nullptr, NTOK, H_, H_/2, H_, H_);
        add_ln3_kernel<<<NTOK, 256, 0, stream>>>(h, kb, kb2, g_attn, b_attn, xa, xa_b);
        mfma_gemm_kernel<128,64,4,2,1,0,1><<<gi, 256, 0, stream>>>(
            xa_b, WiT, bi, nullptr, ff1_b, NTOK, I_, H_, H_, H_);
        mfma_gemm_kernel<128,64,4,2,0,1,0><<<gff2, 256, 0, stream>>>(
            ff1_b, WdT, bd, kb, nullptr, NTOK, H_, I_/2, I_, I_);
        add_ln3_kernel<<<NTOK, 256, 0, stream>>>(xa, kb, kb2, g_out, b_out, h, h_b);
    }

    hipMemcpyAsync(d_out, h, NT * sizeof(float), hipMemcpyDeviceToDevice, stream);
    pooled_kernel<<<dim3(3, 8), 256, 0, stream>>>(h, Wp, bp, (float*)d_out + NT);
}